// Round 4
// baseline (197.522 us; speedup 1.0000x reference)
//
#include <hip/hip_runtime.h>
#include <stdint.h>

#define NN 4096
#define FF 256
#define HH 4
#define DD 64
#define NEG 0.2f
#define LOG2E 1.4426950408889634f

#define ITILE 32
#define NS 8
#define JR (NN / NS)            // 512

typedef __attribute__((ext_vector_type(8))) short short8;
typedef __attribute__((ext_vector_type(4))) float f32x4;
typedef __attribute__((ext_vector_type(16))) float f32x16;

__device__ __forceinline__ uint16_t bf16_rh(float f) {
    uint32_t u = __float_as_uint(f);
    return (uint16_t)((u + 0x8000u) >> 16);
}
__device__ __forceinline__ uint32_t pk2(float a, float b) {
    uint32_t ua = __float_as_uint(a) + 0x8000u;
    uint32_t ub = __float_as_uint(b) + 0x8000u;
    return (ua >> 16) | (ub & 0xffff0000u);
}
// load 8 consecutive f32, convert to 8 bf16 (round-half-up)
__device__ __forceinline__ short8 ld_bf8(const float* __restrict__ p) {
    float4 v0 = *(const float4*)p;
    float4 v1 = *(const float4*)(p + 4);
    union { uint32_t u[4]; short8 v; } o;
    o.u[0] = pk2(v0.x, v0.y); o.u[1] = pk2(v0.z, v0.w);
    o.u[2] = pk2(v1.x, v1.y); o.u[3] = pk2(v1.z, v1.w);
    return o.v;
}

// ---------------- h = x @ W^T (bf16 MFMA, on-the-fly f32->bf16 conversion) --
// + FUSED s,t dots (log2-scaled) + bf16 transposed H_T + pden zeroing.
// grid (NN/64, HH): blockIdx.y is exactly one head (64 f = one D-range).
__global__ __launch_bounds__(256) void gemm_h(const float* __restrict__ x,
                                              const float* __restrict__ W,
                                              const float* __restrict__ a_src,
                                              const float* __restrict__ a_dst,
                                              float* __restrict__ s,
                                              float* __restrict__ T_T,
                                              uint16_t* __restrict__ H_T,
                                              float* __restrict__ pden) {
    const int tid = threadIdx.x;
    if (blockIdx.y == 0) pden[blockIdx.x * 256 + tid] = 0.f;  // 64 blk * 256 = NN*HH
    const int w = tid >> 6, l = tid & 63;
    const int m = l & 15, q = l >> 4;             // 16x16x32: m=l&15, k=q*8+j
    const int i0 = blockIdx.x * 64 + w * 16;
    const int f0 = blockIdx.y * 64;
    const int hh = blockIdx.y;                    // head index
    f32x4 acc[4];
#pragma unroll
    for (int n = 0; n < 4; n++)
#pragma unroll
        for (int r = 0; r < 4; r++) acc[n][r] = 0.f;
    const float* arow = x + (size_t)(i0 + m) * FF + q * 8;
#pragma unroll
    for (int k0 = 0; k0 < FF; k0 += 32) {
        short8 af = ld_bf8(arow + k0);
#pragma unroll
        for (int n = 0; n < 4; n++) {
            short8 bf = ld_bf8(W + (size_t)(f0 + n * 16 + m) * FF + k0 + q * 8);
            acc[n] = __builtin_amdgcn_mfma_f32_16x16x32_bf16(af, bf, acc[n], 0, 0, 0);
        }
    }
    // ---- fused epilogue: s,t dots (log2-scaled) ----
    const float* as = a_src + hh * DD;
    const float* ad = a_dst + hh * DD;
    float av[4], dv[4];
#pragma unroll
    for (int n = 0; n < 4; n++) { av[n] = as[n * 16 + m]; dv[n] = ad[n * 16 + m]; }
#pragma unroll
    for (int r = 0; r < 4; r++) {
        float vs = 0.f, vd = 0.f;
#pragma unroll
        for (int n = 0; n < 4; n++) {
            vs = fmaf(acc[n][r], av[n], vs);
            vd = fmaf(acc[n][r], dv[n], vd);
        }
#pragma unroll
        for (int off = 1; off < 16; off <<= 1) {  // reduce across m
            vs += __shfl_xor(vs, off, 64);
            vd += __shfl_xor(vd, off, 64);
        }
        if (m == 0) {
            const int i = i0 + q * 4 + r;         // C: col=l&15 -> f, row=q*4+r -> i
            s[(size_t)i * HH + hh] = vs * LOG2E;  // log2-domain scores
            T_T[(size_t)hh * NN + i] = vd * LOG2E;
        }
    }
    // ---- fused epilogue: bf16 transposed H_T[f][i] ----
#pragma unroll
    for (int n = 0; n < 4; n++) {
        ushort4 o;
        o.x = bf16_rh(acc[n][0]); o.y = bf16_rh(acc[n][1]);
        o.z = bf16_rh(acc[n][2]); o.w = bf16_rh(acc[n][3]);
        *(ushort4*)(H_T + (size_t)(f0 + n * 16 + m) * NN + i0 + q * 4) = o;
    }
}

// ---------------- fused scores -> exp2 -> P -> MFMA PV, BARRIER-FREE --------
// block: 32 i x 512 j-slice; wave w = head w. NO LDS, NO __syncthreads:
// lane (m,q) of wave w needs adj[i0+m][jg..jg+7] -- contiguous, loaded
// directly as two float4. The 2 q-halves of a row share one 64B line; the 4
// head-waves reuse the same lines via L1/L2. Waves free-run so resident
// waves cover each other's VMEM latency (the 2-phase lockstep stall that
// capped R0-R3 at ~30% VALUBusy is structurally removed).
__global__ __launch_bounds__(256, 4) void gat_main(
    const float* __restrict__ adj, const uint16_t* __restrict__ H_T,
    const float* __restrict__ s, const float* __restrict__ T_T,
    float* __restrict__ pden, uint16_t* __restrict__ part) {
    const int tid = threadIdx.x;
    const int w = tid >> 6, l = tid & 63;
    const int m = l & 31, q = l >> 5;             // 32x32x16: m=l&31, k=q*8+j
    // bijective XCD swizzle (nwg % 8 == 0): same-XCD blocks share a j-slice
    constexpr int NWG = (NN / ITILE) * NS;
    const int orig = blockIdx.y * (NN / ITILE) + blockIdx.x;
    const int swz = (orig & 7) * (NWG / 8) + (orig >> 3);
    const int i0 = (swz & (NN / ITILE - 1)) * ITILE;
    const int sl = swz / (NN / ITILE);
    const int jb = sl * JR;

    const float sS = s[(size_t)(i0 + m) * HH + w];  // *log2e already
    const float sB = NEG * sS;
    float den = 0.f;
    f32x16 acc0, acc1;
#pragma unroll
    for (int r = 0; r < 16; r++) { acc0[r] = 0.f; acc1[r] = 0.f; }
    const float* trow = T_T + (size_t)w * NN;
    const uint16_t* b0row = H_T + (size_t)(w * DD + m) * NN;
    const uint16_t* b1row = H_T + (size_t)(w * DD + 32 + m) * NN;
    const float* ar = adj + (size_t)(i0 + m) * NN;  // this lane's own adj row

#pragma unroll 2
    for (int it = 0; it < JR / 16; ++it) {
        const int jg = jb + it * 16 + q * 8;      // lane's first j (global)
        float4 a0 = *(const float4*)(ar + jg);
        float4 a1 = *(const float4*)(ar + jg + 4);
        float4 t0 = *(const float4*)(trow + jg);
        float4 t1 = *(const float4*)(trow + jg + 4);
        short8 bf0 = *(const short8*)(b0row + jg);
        short8 bf1 = *(const short8*)(b1row + jg);
        float aa[8] = {a0.x, a0.y, a0.z, a0.w, a1.x, a1.y, a1.z, a1.w};
        float tt[8] = {t0.x, t0.y, t0.z, t0.w, t1.x, t1.y, t1.z, t1.w};
        uint32_t pk_[4];
#pragma unroll
        for (int jj = 0; jj < 8; jj += 2) {
            float tv0 = tt[jj], tv1 = tt[jj + 1];
            // lrelu in log2 domain: max(S+T, 0.2*(S+T)); exp2 direct
            float x0 = sS + tv0,            x1 = sS + tv1;
            float z0 = fmaf(NEG, tv0, sB),  z1 = fmaf(NEG, tv1, sB);
            float lr0 = fmaxf(x0, z0), lr1 = fmaxf(x1, z1);
            float e0, e1;
            asm("v_exp_f32 %0, %1" : "=v"(e0) : "v"(lr0));
            asm("v_exp_f32 %0, %1" : "=v"(e1) : "v"(lr1));
            e0 = (aa[jj] > 0.f) ? e0 : 0.f;
            e1 = (aa[jj + 1] > 0.f) ? e1 : 0.f;
            den += e0 + e1;
            pk_[jj >> 1] = pk2(e0 * aa[jj], e1 * aa[jj + 1]);
        }
        union { uint32_t u[4]; short8 v; } afu;
#pragma unroll
        for (int c = 0; c < 4; c++) afu.u[c] = pk_[c];
        acc0 = __builtin_amdgcn_mfma_f32_32x32x16_bf16(afu.v, bf0, acc0, 0, 0, 0);
        acc1 = __builtin_amdgcn_mfma_f32_32x32x16_bf16(afu.v, bf1, acc1, 0, 0, 0);
    }
    den += __shfl_down(den, 32, 64);              // lanes l and l+32 share m
    if (l < 32) atomicAdd(&pden[(size_t)(i0 + m) * HH + w], den);
    uint16_t* pbase = part + (size_t)sl * NN * FF;
#pragma unroll
    for (int reg = 0; reg < 16; reg++) {
        int row = (reg & 3) + 8 * (reg >> 2) + 4 * q;  // C: col=l&31, verified m74
        pbase[(size_t)(i0 + row) * FF + w * DD + m]      = bf16_rh(acc0[reg]);
        pbase[(size_t)(i0 + row) * FF + w * DD + 32 + m] = bf16_rh(acc1[reg]);
    }
}

// ---------------- sum slice partials, divide by denom (vectorized) ----------
// block: 4 i-rows x 64 lanes; thread handles 4 consecutive f via ushort4.
__global__ __launch_bounds__(256) void finalize(const uint16_t* __restrict__ part,
                                                const float* __restrict__ pden,
                                                float* __restrict__ out) {
    const int i = blockIdx.x * 4 + (threadIdx.x >> 6);
    const int fq = (threadIdx.x & 63) * 4;
    float s0 = 0.f, s1 = 0.f, s2 = 0.f, s3 = 0.f;
#pragma unroll
    for (int sl = 0; sl < NS; sl++) {
        ushort4 v = *(const ushort4*)(part + (size_t)sl * NN * FF + (size_t)i * FF + fq);
        s0 += __uint_as_float(((uint32_t)v.x) << 16);
        s1 += __uint_as_float(((uint32_t)v.y) << 16);
        s2 += __uint_as_float(((uint32_t)v.z) << 16);
        s3 += __uint_as_float(((uint32_t)v.w) << 16);
    }
    float d = pden[(size_t)i * HH + (fq >> 6)];
    float inv = (d > 0.f) ? 1.f / d : 0.f;
    *(float4*)(out + (size_t)i * FF + fq) =
        make_float4(s0 * inv, s1 * inv, s2 * inv, s3 * inv);
}

extern "C" void kernel_launch(void* const* d_in, const int* in_sizes, int n_in,
                              void* d_out, int out_size, void* d_ws, size_t ws_size,
                              hipStream_t stream) {
    const float* x     = (const float*)d_in[0];
    const float* adj   = (const float*)d_in[1];
    const float* W     = (const float*)d_in[2];
    const float* a_src = (const float*)d_in[3];
    const float* a_dst = (const float*)d_in[4];
    float* out = (float*)d_out;

    char* ws = (char*)d_ws;
    uint16_t* H_T  = (uint16_t*)ws;                                // 2 MB
    float*    s    = (float*)(ws + (2u << 20));                    // 64 KB
    float*    T_T  = s + (size_t)NN * HH;                          // 64 KB
    float*    pden = T_T + (size_t)HH * NN;                        // 64 KB
    uint16_t* part = (uint16_t*)(ws + (3u << 20));                 // NS * 2 MB = 16 MB

    gemm_h<<<dim3(NN / 64, HH), 256, 0, stream>>>(x, W, a_src, a_dst, s, T_T, H_T, pden);
    gat_main<<<dim3(NN / ITILE, NS), 256, 0, stream>>>(adj, H_T, s, T_T, pden, part);
    finalize<<<NN / 4, 256, 0, stream>>>(part, pden, out);
}

// Round 5
// 143.177 us; speedup vs baseline: 1.3796x; 1.3796x over previous
//
#include <hip/hip_runtime.h>
#include <stdint.h>

#define NN 4096
#define FF 256
#define HH 4
#define DD 64
#define NEG 0.2f
#define LOG2E 1.4426950408889634f

#define ITILE 32
#define NS 8
#define JR (NN / NS)            // 512
#define CJ 64
#define NCH (JR / CJ)           // 8
#define NB (NN / 8)             // 512 j-blocks of 8

typedef __attribute__((ext_vector_type(8))) short short8;
typedef __attribute__((ext_vector_type(4))) float f32x4;
typedef __attribute__((ext_vector_type(16))) float f32x16;

__device__ __forceinline__ uint16_t bf16_rh(float f) {
    uint32_t u = __float_as_uint(f);
    return (uint16_t)((u + 0x8000u) >> 16);
}
__device__ __forceinline__ uint32_t pk2(float a, float b) {
    uint32_t ua = __float_as_uint(a) + 0x8000u;
    uint32_t ub = __float_as_uint(b) + 0x8000u;
    return (ua >> 16) | (ub & 0xffff0000u);
}
// load 8 consecutive f32, convert to 8 bf16 (round-half-up)
__device__ __forceinline__ short8 ld_bf8(const float* __restrict__ p) {
    float4 v0 = *(const float4*)p;
    float4 v1 = *(const float4*)(p + 4);
    union { uint32_t u[4]; short8 v; } o;
    o.u[0] = pk2(v0.x, v0.y); o.u[1] = pk2(v0.z, v0.w);
    o.u[2] = pk2(v1.x, v1.y); o.u[3] = pk2(v1.z, v1.w);
    return o.v;
}

// ---------------- h = x @ W^T (bf16 MFMA, on-the-fly f32->bf16 conversion) --
// + FUSED s,t dots (log2-scaled) + B-fragment-packed H + pden zeroing.
// grid (NN/64, HH): blockIdx.y is exactly one head (64 f = one D-range).
// Bf layout: [head][iblk = i/8][f_local 0..63][jj = i%8] -- exactly the
// 32x32x16 MFMA B-operand order, so gat_main's B-load is CONTIGUOUS per lane
// group (R4 lesson: divergent per-lane rows = 32 line-requests/instr = the
// hidden serializer; this layout makes it 2).
__global__ __launch_bounds__(256) void gemm_h(const float* __restrict__ x,
                                              const float* __restrict__ W,
                                              const float* __restrict__ a_src,
                                              const float* __restrict__ a_dst,
                                              float* __restrict__ s,
                                              float* __restrict__ T_T,
                                              uint16_t* __restrict__ Bf,
                                              float* __restrict__ pden) {
    const int tid = threadIdx.x;
    if (blockIdx.y == 0) pden[blockIdx.x * 256 + tid] = 0.f;  // 64 blk * 256 = NN*HH
    const int w = tid >> 6, l = tid & 63;
    const int m = l & 15, q = l >> 4;             // 16x16x32: m=l&15, k=q*8+j
    const int i0 = blockIdx.x * 64 + w * 16;
    const int f0 = blockIdx.y * 64;
    const int hh = blockIdx.y;                    // head index
    f32x4 acc[4];
#pragma unroll
    for (int n = 0; n < 4; n++)
#pragma unroll
        for (int r = 0; r < 4; r++) acc[n][r] = 0.f;
    const float* arow = x + (size_t)(i0 + m) * FF + q * 8;
#pragma unroll
    for (int k0 = 0; k0 < FF; k0 += 32) {
        short8 af = ld_bf8(arow + k0);
#pragma unroll
        for (int n = 0; n < 4; n++) {
            short8 bf = ld_bf8(W + (size_t)(f0 + n * 16 + m) * FF + k0 + q * 8);
            acc[n] = __builtin_amdgcn_mfma_f32_16x16x32_bf16(af, bf, acc[n], 0, 0, 0);
        }
    }
    // ---- fused epilogue: s,t dots (log2-scaled) ----
    const float* as = a_src + hh * DD;
    const float* ad = a_dst + hh * DD;
    float av[4], dv[4];
#pragma unroll
    for (int n = 0; n < 4; n++) { av[n] = as[n * 16 + m]; dv[n] = ad[n * 16 + m]; }
#pragma unroll
    for (int r = 0; r < 4; r++) {
        float vs = 0.f, vd = 0.f;
#pragma unroll
        for (int n = 0; n < 4; n++) {
            vs = fmaf(acc[n][r], av[n], vs);
            vd = fmaf(acc[n][r], dv[n], vd);
        }
#pragma unroll
        for (int off = 1; off < 16; off <<= 1) {  // reduce across m
            vs += __shfl_xor(vs, off, 64);
            vd += __shfl_xor(vd, off, 64);
        }
        if (m == 0) {
            const int i = i0 + q * 4 + r;         // C: col=l&15 -> f, row=q*4+r -> i
            s[(size_t)i * HH + hh] = vs * LOG2E;  // log2-domain scores
            T_T[(size_t)hh * NN + i] = vd * LOG2E;
        }
    }
    // ---- fused epilogue: B-fragment-packed store ----
    // value acc[n][r] = h[i=i0+q*4+r][f=f0+n*16+m]; iblk=i/8, jj=i%8.
    const int iblk = blockIdx.x * 8 + w * 2 + (q >> 1);
    const int jjo  = (q & 1) * 4;                 // r=0..3 contiguous -> ushort4
#pragma unroll
    for (int n = 0; n < 4; n++) {
        ushort4 o;
        o.x = bf16_rh(acc[n][0]); o.y = bf16_rh(acc[n][1]);
        o.z = bf16_rh(acc[n][2]); o.w = bf16_rh(acc[n][3]);
        *(ushort4*)(Bf + (((size_t)hh * NB + iblk) * 64 + n * 16 + m) * 8 + jjo) = o;
    }
}

// ---------------- fused scores -> exp2 -> P -> MFMA PV ----------------------
// block: 32 i x 512 j-slice; wave w = head w. adj double-buffered in LDS
// (ONE barrier per 64-j chunk) with register prefetch 2 chunks ahead.
// B-operand from fragment-packed Bf: lane group reads 512B contiguous.
// Scores in log2-domain, exp2 direct (no max-sub; scale cancels in softmax).
__global__ __launch_bounds__(256, 4) void gat_main(
    const float* __restrict__ adj, const uint16_t* __restrict__ Bf,
    const float* __restrict__ s, const float* __restrict__ T_T,
    float* __restrict__ pden, uint16_t* __restrict__ part) {
    __shared__ float adj_s[2][CJ][ITILE + 1];     // 2 x 64 x 33 x 4B = 16.9 KB
    const int tid = threadIdx.x;
    const int w = tid >> 6, l = tid & 63;
    const int m = l & 31, q = l >> 5;             // 32x32x16: m=l&31, k=q*8+j
    // bijective XCD swizzle (nwg % 8 == 0): same-XCD blocks share a j-slice
    constexpr int NWG = (NN / ITILE) * NS;
    const int orig = blockIdx.y * (NN / ITILE) + blockIdx.x;
    const int swz = (orig & 7) * (NWG / 8) + (orig >> 3);
    const int i0 = (swz & (NN / ITILE - 1)) * ITILE;
    const int sl = swz / (NN / ITILE);
    const int jb = sl * JR;

    const float sS = s[(size_t)(i0 + m) * HH + w];  // *log2e already
    const float sB = NEG * sS;
    float den = 0.f;
    f32x16 acc0, acc1;
#pragma unroll
    for (int r = 0; r < 16; r++) { acc0[r] = 0.f; acc1[r] = 0.f; }
    const float* trow = T_T + (size_t)w * NN;
    const uint16_t* bbase = Bf + (size_t)w * NB * 512;  // 512 u16 per jblk

    // staging geometry: thread stages adj[i0+is][jc+j8 .. +7] (2 float4)
    const int is = tid >> 3, j8 = (tid & 7) * 8;
    const float* arow = adj + (size_t)(i0 + is) * NN + j8;

    float4 p0 = *(const float4*)(arow + jb);
    float4 p1 = *(const float4*)(arow + jb + 4);
    adj_s[0][j8 + 0][is] = p0.x; adj_s[0][j8 + 1][is] = p0.y;
    adj_s[0][j8 + 2][is] = p0.z; adj_s[0][j8 + 3][is] = p0.w;
    adj_s[0][j8 + 4][is] = p1.x; adj_s[0][j8 + 5][is] = p1.y;
    adj_s[0][j8 + 6][is] = p1.z; adj_s[0][j8 + 7][is] = p1.w;
    p0 = *(const float4*)(arow + jb + CJ);
    p1 = *(const float4*)(arow + jb + CJ + 4);
    __syncthreads();

    for (int c = 0; c < NCH; ++c) {
        const int jc = jb + c * CJ;
        const int cur = c & 1;
        if (c + 1 < NCH) {                        // write chunk c+1 into other buf
            const int nb = cur ^ 1;
            adj_s[nb][j8 + 0][is] = p0.x; adj_s[nb][j8 + 1][is] = p0.y;
            adj_s[nb][j8 + 2][is] = p0.z; adj_s[nb][j8 + 3][is] = p0.w;
            adj_s[nb][j8 + 4][is] = p1.x; adj_s[nb][j8 + 5][is] = p1.y;
            adj_s[nb][j8 + 6][is] = p1.z; adj_s[nb][j8 + 7][is] = p1.w;
            if (c + 2 < NCH) {                    // prefetch chunk c+2 -> regs
                p0 = *(const float4*)(arow + jc + 2 * CJ);
                p1 = *(const float4*)(arow + jc + 2 * CJ + 4);
            }
        }
#pragma unroll
        for (int kk = 0; kk < CJ; kk += 16) {
            const int jg = jc + kk + q * 8;       // lane's first j (global)
            const int jblk = ((jc + kk) >> 3) + q;
            float4 t0 = *(const float4*)(trow + jg);
            float4 t1 = *(const float4*)(trow + jg + 4);
            short8 bf0 = *(const short8*)(bbase + (size_t)jblk * 512 + m * 8);
            short8 bf1 = *(const short8*)(bbase + (size_t)jblk * 512 + (32 + m) * 8);
            float tt[8] = {t0.x, t0.y, t0.z, t0.w, t1.x, t1.y, t1.z, t1.w};
            uint32_t pk_[4];
#pragma unroll
            for (int jj = 0; jj < 8; jj += 2) {
                const int rr = kk + q * 8 + jj;
                float a0 = adj_s[cur][rr][m], a1 = adj_s[cur][rr + 1][m];
                float tv0 = tt[jj], tv1 = tt[jj + 1];
                // lrelu in log2 domain: max(S+T, 0.2*(S+T)); exp2 direct
                float x0 = sS + tv0,           x1 = sS + tv1;
                float z0 = fmaf(NEG, tv0, sB), z1 = fmaf(NEG, tv1, sB);
                float lr0 = fmaxf(x0, z0), lr1 = fmaxf(x1, z1);
                float e0, e1;
                asm("v_exp_f32 %0, %1" : "=v"(e0) : "v"(lr0));
                asm("v_exp_f32 %0, %1" : "=v"(e1) : "v"(lr1));
                e0 = (a0 > 0.f) ? e0 : 0.f;
                e1 = (a1 > 0.f) ? e1 : 0.f;
                den += e0 + e1;
                pk_[jj >> 1] = pk2(e0 * a0, e1 * a1);
            }
            union { uint32_t u[4]; short8 v; } afu;
#pragma unroll
            for (int c4 = 0; c4 < 4; c4++) afu.u[c4] = pk_[c4];
            acc0 = __builtin_amdgcn_mfma_f32_32x32x16_bf16(afu.v, bf0, acc0, 0, 0, 0);
            acc1 = __builtin_amdgcn_mfma_f32_32x32x16_bf16(afu.v, bf1, acc1, 0, 0, 0);
        }
        __syncthreads();
    }
    den += __shfl_down(den, 32, 64);              // lanes l and l+32 share m
    if (l < 32) atomicAdd(&pden[(size_t)(i0 + m) * HH + w], den);
    uint16_t* pbase = part + (size_t)sl * NN * FF;
#pragma unroll
    for (int reg = 0; reg < 16; reg++) {
        int row = (reg & 3) + 8 * (reg >> 2) + 4 * q;  // C: col=l&31, verified m74
        pbase[(size_t)(i0 + row) * FF + w * DD + m]      = bf16_rh(acc0[reg]);
        pbase[(size_t)(i0 + row) * FF + w * DD + 32 + m] = bf16_rh(acc1[reg]);
    }
}

// ---------------- sum slice partials, divide by denom (vectorized) ----------
// block: 4 i-rows x 64 lanes; thread handles 4 consecutive f via ushort4.
__global__ __launch_bounds__(256) void finalize(const uint16_t* __restrict__ part,
                                                const float* __restrict__ pden,
                                                float* __restrict__ out) {
    const int i = blockIdx.x * 4 + (threadIdx.x >> 6);
    const int fq = (threadIdx.x & 63) * 4;
    float s0 = 0.f, s1 = 0.f, s2 = 0.f, s3 = 0.f;
#pragma unroll
    for (int sl = 0; sl < NS; sl++) {
        ushort4 v = *(const ushort4*)(part + (size_t)sl * NN * FF + (size_t)i * FF + fq);
        s0 += __uint_as_float(((uint32_t)v.x) << 16);
        s1 += __uint_as_float(((uint32_t)v.y) << 16);
        s2 += __uint_as_float(((uint32_t)v.z) << 16);
        s3 += __uint_as_float(((uint32_t)v.w) << 16);
    }
    float d = pden[(size_t)i * HH + (fq >> 6)];
    float inv = (d > 0.f) ? 1.f / d : 0.f;
    *(float4*)(out + (size_t)i * FF + fq) =
        make_float4(s0 * inv, s1 * inv, s2 * inv, s3 * inv);
}

extern "C" void kernel_launch(void* const* d_in, const int* in_sizes, int n_in,
                              void* d_out, int out_size, void* d_ws, size_t ws_size,
                              hipStream_t stream) {
    const float* x     = (const float*)d_in[0];
    const float* adj   = (const float*)d_in[1];
    const float* W     = (const float*)d_in[2];
    const float* a_src = (const float*)d_in[3];
    const float* a_dst = (const float*)d_in[4];
    float* out = (float*)d_out;

    char* ws = (char*)d_ws;
    uint16_t* Bf   = (uint16_t*)ws;                                // 2 MB
    float*    s    = (float*)(ws + (2u << 20));                    // 64 KB
    float*    T_T  = s + (size_t)NN * HH;                          // 64 KB
    float*    pden = T_T + (size_t)HH * NN;                        // 64 KB
    uint16_t* part = (uint16_t*)(ws + (3u << 20));                 // NS * 2 MB = 16 MB

    gemm_h<<<dim3(NN / 64, HH), 256, 0, stream>>>(x, W, a_src, a_dst, s, T_T, Bf, pden);
    gat_main<<<dim3(NN / ITILE, NS), 256, 0, stream>>>(adj, Bf, s, T_T, pden, part);
    finalize<<<NN / 4, 256, 0, stream>>>(part, pden, out);
}

// Round 6
// 134.728 us; speedup vs baseline: 1.4661x; 1.0627x over previous
//
#include <hip/hip_runtime.h>
#include <stdint.h>

#define NN 4096
#define FF 256
#define HH 4
#define DD 64
#define NEG 0.2f
#define LOG2E 1.4426950408889634f

#define ITILE 32
#define NS 8
#define JR (NN / NS)            // 512
#define CJ 128
#define NCH (JR / CJ)           // 4
#define NB (NN / 8)             // 512 j-blocks of 8

typedef __attribute__((ext_vector_type(8))) short short8;
typedef __attribute__((ext_vector_type(4))) float f32x4;
typedef __attribute__((ext_vector_type(16))) float f32x16;

__device__ __forceinline__ uint16_t bf16_rh(float f) {
    uint32_t u = __float_as_uint(f);
    return (uint16_t)((u + 0x8000u) >> 16);
}
__device__ __forceinline__ uint32_t pk2(float a, float b) {
    uint32_t ua = __float_as_uint(a) + 0x8000u;
    uint32_t ub = __float_as_uint(b) + 0x8000u;
    return (ua >> 16) | (ub & 0xffff0000u);
}
__device__ __forceinline__ ushort4 cvt_u4(float4 v) {
    ushort4 o;
    o.x = bf16_rh(v.x); o.y = bf16_rh(v.y);
    o.z = bf16_rh(v.z); o.w = bf16_rh(v.w);
    return o;
}

// ---------------- h = x @ W^T (bf16 MFMA) -----------------------------------
// R5 post-mortem: old version ran 1 block/CU (zero TLP) with 16-way
// lane-divergent operand loads straight from global -- the R4 pathology.
// Rebuilt on the canonical pattern: x-tile and W-slice are CONTIGUOUS 64KB
// each -> staged coalesced (thread t loads float4 p*256+t) into LDS as bf16,
// fragments then read from LDS (pad +8: b128 reads spread across all 8
// 4-bank groups, conflict-free minimum). Epilogue: s,t dots (log2-scaled),
// B-fragment-packed Bf store, pden zeroing. grid (NN/64, HH).
__global__ __launch_bounds__(256) void gemm_h(const float* __restrict__ x,
                                              const float* __restrict__ W,
                                              const float* __restrict__ a_src,
                                              const float* __restrict__ a_dst,
                                              float* __restrict__ s,
                                              float* __restrict__ T_T,
                                              uint16_t* __restrict__ Bf,
                                              float* __restrict__ pden) {
    __shared__ uint16_t xs[64][264];              // 33 KB
    __shared__ uint16_t wsl[64][264];             // 33 KB
    const int tid = threadIdx.x;
    if (blockIdx.y == 0) pden[blockIdx.x * 256 + tid] = 0.f;  // 64 blk * 256 = NN*HH
    const int i0g = blockIdx.x * 64;
    const int f0 = blockIdx.y * 64;
    const int hh = blockIdx.y;                    // head index
    const float* xsrc = x + (size_t)i0g * FF;     // contiguous 64x256 tile
    const float* wsrc = W + (size_t)f0 * FF;      // contiguous 64x256 slice
    {
        const int rw = tid >> 6, c4 = (tid & 63) * 4;
#pragma unroll
        for (int p = 0; p < 16; p++) {
            float4 vx = ((const float4*)xsrc)[p * 256 + tid];
            float4 vw = ((const float4*)wsrc)[p * 256 + tid];
            *(ushort4*)&xs[p * 4 + rw][c4] = cvt_u4(vx);
            *(ushort4*)&wsl[p * 4 + rw][c4] = cvt_u4(vw);
        }
    }
    __syncthreads();
    const int w = tid >> 6, l = tid & 63;
    const int m = l & 15, q = l >> 4;             // 16x16x32: m=l&15, k=q*8+j
    const int i0 = i0g + w * 16;
    f32x4 acc[4];
#pragma unroll
    for (int n = 0; n < 4; n++)
#pragma unroll
        for (int r = 0; r < 4; r++) acc[n][r] = 0.f;
    const uint16_t* ax = &xs[w * 16 + m][q * 8];
#pragma unroll
    for (int k0 = 0; k0 < 8; k0++) {
        short8 af = *(const short8*)(ax + k0 * 32);
#pragma unroll
        for (int n = 0; n < 4; n++) {
            short8 bf = *(const short8*)&wsl[n * 16 + m][k0 * 32 + q * 8];
            acc[n] = __builtin_amdgcn_mfma_f32_16x16x32_bf16(af, bf, acc[n], 0, 0, 0);
        }
    }
    // ---- fused epilogue: s,t dots (log2-scaled) ----
    const float* as = a_src + hh * DD;
    const float* ad = a_dst + hh * DD;
    float av[4], dv[4];
#pragma unroll
    for (int n = 0; n < 4; n++) { av[n] = as[n * 16 + m]; dv[n] = ad[n * 16 + m]; }
#pragma unroll
    for (int r = 0; r < 4; r++) {
        float vs = 0.f, vd = 0.f;
#pragma unroll
        for (int n = 0; n < 4; n++) {
            vs = fmaf(acc[n][r], av[n], vs);
            vd = fmaf(acc[n][r], dv[n], vd);
        }
#pragma unroll
        for (int off = 1; off < 16; off <<= 1) {  // reduce across m
            vs += __shfl_xor(vs, off, 64);
            vd += __shfl_xor(vd, off, 64);
        }
        if (m == 0) {
            const int i = i0 + q * 4 + r;         // C: col=l&15 -> f, row=q*4+r -> i
            s[(size_t)i * HH + hh] = vs * LOG2E;  // log2-domain scores
            T_T[(size_t)hh * NN + i] = vd * LOG2E;
        }
    }
    // ---- fused epilogue: B-fragment-packed store ----
    // value acc[n][r] = h[i=i0+q*4+r][f=f0+n*16+m]; iblk=i/8, jj=i%8.
    const int iblk = blockIdx.x * 8 + w * 2 + (q >> 1);
    const int jjo  = (q & 1) * 4;                 // r=0..3 contiguous -> ushort4
#pragma unroll
    for (int n = 0; n < 4; n++) {
        ushort4 o;
        o.x = bf16_rh(acc[n][0]); o.y = bf16_rh(acc[n][1]);
        o.z = bf16_rh(acc[n][2]); o.w = bf16_rh(acc[n][3]);
        *(ushort4*)(Bf + (((size_t)hh * NB + iblk) * 64 + n * 16 + m) * 8 + jjo) = o;
    }
}

// ---------------- fused scores -> exp2 -> P -> MFMA PV ----------------------
// block: 32 i x 512 j-slice; wave w = head w. adj double-buffered in LDS,
// CJ=128 (ONE barrier per 128 j -- half of R5's barrier count) with register
// prefetch one chunk ahead. B-operand from fragment-packed Bf (contiguous
// 512B per lane group). Scores in log2-domain, exp2 direct.
__global__ __launch_bounds__(256, 4) void gat_main(
    const float* __restrict__ adj, const uint16_t* __restrict__ Bf,
    const float* __restrict__ s, const float* __restrict__ T_T,
    float* __restrict__ pden, uint16_t* __restrict__ part) {
    __shared__ float adj_s[2][CJ][ITILE + 1];     // 2 x 128 x 33 x 4B = 33 KB
    const int tid = threadIdx.x;
    const int w = tid >> 6, l = tid & 63;
    const int m = l & 31, q = l >> 5;             // 32x32x16: m=l&31, k=q*8+j
    // bijective XCD swizzle (nwg % 8 == 0): same-XCD blocks share a j-slice
    constexpr int NWG = (NN / ITILE) * NS;
    const int orig = blockIdx.y * (NN / ITILE) + blockIdx.x;
    const int swz = (orig & 7) * (NWG / 8) + (orig >> 3);
    const int i0 = (swz & (NN / ITILE - 1)) * ITILE;
    const int sl = swz / (NN / ITILE);
    const int jb = sl * JR;

    const float sS = s[(size_t)(i0 + m) * HH + w];  // *log2e already
    const float sB = NEG * sS;
    float den = 0.f;
    f32x16 acc0, acc1;
#pragma unroll
    for (int r = 0; r < 16; r++) { acc0[r] = 0.f; acc1[r] = 0.f; }
    const float* trow = T_T + (size_t)w * NN;
    const uint16_t* bbase = Bf + (size_t)w * NB * 512;  // 512 u16 per jblk

    // staging geometry: thread stages adj[i0+is][jc+j16 .. +15] (4 float4)
    const int is = tid >> 3, j16 = (tid & 7) * 16;
    const float* arow = adj + (size_t)(i0 + is) * NN + j16;

    float4 pre[4];
#pragma unroll
    for (int c4 = 0; c4 < 4; c4++) pre[c4] = *(const float4*)(arow + jb + c4 * 4);
#pragma unroll
    for (int c4 = 0; c4 < 4; c4++) {
        adj_s[0][j16 + c4 * 4 + 0][is] = pre[c4].x;
        adj_s[0][j16 + c4 * 4 + 1][is] = pre[c4].y;
        adj_s[0][j16 + c4 * 4 + 2][is] = pre[c4].z;
        adj_s[0][j16 + c4 * 4 + 3][is] = pre[c4].w;
    }
#pragma unroll
    for (int c4 = 0; c4 < 4; c4++) pre[c4] = *(const float4*)(arow + jb + CJ + c4 * 4);
    __syncthreads();

    for (int c = 0; c < NCH; ++c) {
        const int jc = jb + c * CJ;
        const int cur = c & 1;
        if (c + 1 < NCH) {                        // write chunk c+1 into other buf
            const int nb = cur ^ 1;
#pragma unroll
            for (int c4 = 0; c4 < 4; c4++) {
                adj_s[nb][j16 + c4 * 4 + 0][is] = pre[c4].x;
                adj_s[nb][j16 + c4 * 4 + 1][is] = pre[c4].y;
                adj_s[nb][j16 + c4 * 4 + 2][is] = pre[c4].z;
                adj_s[nb][j16 + c4 * 4 + 3][is] = pre[c4].w;
            }
            if (c + 2 < NCH) {                    // prefetch chunk c+2 -> regs
#pragma unroll
                for (int c4 = 0; c4 < 4; c4++)
                    pre[c4] = *(const float4*)(arow + jc + 2 * CJ + c4 * 4);
            }
        }
#pragma unroll
        for (int kk = 0; kk < CJ; kk += 16) {
            const int jg = jc + kk + q * 8;       // lane's first j (global)
            const int jblk = ((jc + kk) >> 3) + q;
            float4 t0 = *(const float4*)(trow + jg);
            float4 t1 = *(const float4*)(trow + jg + 4);
            short8 bf0 = *(const short8*)(bbase + (size_t)jblk * 512 + m * 8);
            short8 bf1 = *(const short8*)(bbase + (size_t)jblk * 512 + (32 + m) * 8);
            float tt[8] = {t0.x, t0.y, t0.z, t0.w, t1.x, t1.y, t1.z, t1.w};
            uint32_t pk_[4];
#pragma unroll
            for (int jj = 0; jj < 8; jj += 2) {
                const int rr = kk + q * 8 + jj;
                float a0 = adj_s[cur][rr][m], a1 = adj_s[cur][rr + 1][m];
                float tv0 = tt[jj], tv1 = tt[jj + 1];
                // lrelu in log2 domain: max(S+T, 0.2*(S+T)); exp2 direct
                float x0 = sS + tv0,           x1 = sS + tv1;
                float z0 = fmaf(NEG, tv0, sB), z1 = fmaf(NEG, tv1, sB);
                float lr0 = fmaxf(x0, z0), lr1 = fmaxf(x1, z1);
                float e0, e1;
                asm("v_exp_f32 %0, %1" : "=v"(e0) : "v"(lr0));
                asm("v_exp_f32 %0, %1" : "=v"(e1) : "v"(lr1));
                e0 = (a0 > 0.f) ? e0 : 0.f;
                e1 = (a1 > 0.f) ? e1 : 0.f;
                den += e0 + e1;
                pk_[jj >> 1] = pk2(e0 * a0, e1 * a1);
            }
            union { uint32_t u[4]; short8 v; } afu;
#pragma unroll
            for (int c4 = 0; c4 < 4; c4++) afu.u[c4] = pk_[c4];
            acc0 = __builtin_amdgcn_mfma_f32_32x32x16_bf16(afu.v, bf0, acc0, 0, 0, 0);
            acc1 = __builtin_amdgcn_mfma_f32_32x32x16_bf16(afu.v, bf1, acc1, 0, 0, 0);
        }
        __syncthreads();
    }
    den += __shfl_down(den, 32, 64);              // lanes l and l+32 share m
    if (l < 32) atomicAdd(&pden[(size_t)(i0 + m) * HH + w], den);
    uint16_t* pbase = part + (size_t)sl * NN * FF;
#pragma unroll
    for (int reg = 0; reg < 16; reg++) {
        int row = (reg & 3) + 8 * (reg >> 2) + 4 * q;  // C: col=l&31, verified m74
        pbase[(size_t)(i0 + row) * FF + w * DD + m]      = bf16_rh(acc0[reg]);
        pbase[(size_t)(i0 + row) * FF + w * DD + 32 + m] = bf16_rh(acc1[reg]);
    }
}

// ---------------- sum slice partials, divide by denom (vectorized) ----------
// block: 8 i-rows x 32 lanes; thread handles 8 consecutive f via short8 (16B).
__global__ __launch_bounds__(256) void finalize(const uint16_t* __restrict__ part,
                                                const float* __restrict__ pden,
                                                float* __restrict__ out) {
    const int i = blockIdx.x * 8 + (threadIdx.x >> 5);
    const int f8 = (threadIdx.x & 31) * 8;
    float acc[8];
#pragma unroll
    for (int e = 0; e < 8; e++) acc[e] = 0.f;
#pragma unroll
    for (int sl = 0; sl < NS; sl++) {
        union { short8 v; uint16_t u[8]; } b;
        b.v = *(const short8*)(part + (size_t)sl * NN * FF + (size_t)i * FF + f8);
#pragma unroll
        for (int e = 0; e < 8; e++)
            acc[e] += __uint_as_float(((uint32_t)b.u[e]) << 16);
    }
    float d = pden[(size_t)i * HH + (f8 >> 6)];
    float inv = (d > 0.f) ? 1.f / d : 0.f;
    *(float4*)(out + (size_t)i * FF + f8) =
        make_float4(acc[0] * inv, acc[1] * inv, acc[2] * inv, acc[3] * inv);
    *(float4*)(out + (size_t)i * FF + f8 + 4) =
        make_float4(acc[4] * inv, acc[5] * inv, acc[6] * inv, acc[7] * inv);
}

extern "C" void kernel_launch(void* const* d_in, const int* in_sizes, int n_in,
                              void* d_out, int out_size, void* d_ws, size_t ws_size,
                              hipStream_t stream) {
    const float* x     = (const float*)d_in[0];
    const float* adj   = (const float*)d_in[1];
    const float* W     = (const float*)d_in[2];
    const float* a_src = (const float*)d_in[3];
    const float* a_dst = (const float*)d_in[4];
    float* out = (float*)d_out;

    char* ws = (char*)d_ws;
    uint16_t* Bf   = (uint16_t*)ws;                                // 2 MB
    float*    s    = (float*)(ws + (2u << 20));                    // 64 KB
    float*    T_T  = s + (size_t)NN * HH;                          // 64 KB
    float*    pden = T_T + (size_t)HH * NN;                        // 64 KB
    uint16_t* part = (uint16_t*)(ws + (3u << 20));                 // NS * 2 MB = 16 MB

    gemm_h<<<dim3(NN / 64, HH), 256, 0, stream>>>(x, W, a_src, a_dst, s, T_T, Bf, pden);
    gat_main<<<dim3(NN / ITILE, NS), 256, 0, stream>>>(adj, Bf, s, T_T, pden, part);
    finalize<<<NN / 8, 256, 0, stream>>>(part, pden, out);
}

// Round 7
// 129.908 us; speedup vs baseline: 1.5205x; 1.0371x over previous
//
#include <hip/hip_runtime.h>
#include <stdint.h>

#define NN 4096
#define FF 256
#define HH 4
#define DD 64
#define NEG 0.2f
#define LOG2E 1.4426950408889634f

#define ITILE 32
#define NS 8
#define JR (NN / NS)            // 512
#define CJ 128
#define NCH (JR / CJ)           // 4
#define NB (NN / 8)             // 512 j-blocks of 8

typedef __attribute__((ext_vector_type(8))) short short8;
typedef __attribute__((ext_vector_type(4))) float f32x4;
typedef __attribute__((ext_vector_type(16))) float f32x16;

__device__ __forceinline__ uint16_t bf16_rh(float f) {
    uint32_t u = __float_as_uint(f);
    return (uint16_t)((u + 0x8000u) >> 16);
}
// single-instr packed f32x2 -> bf16x2 (RNE); T12 recipe, no builtin on gfx950
__device__ __forceinline__ uint32_t cvtpk(float lo, float hi) {
    uint32_t r;
    asm("v_cvt_pk_bf16_f32 %0, %1, %2" : "=v"(r) : "v"(lo), "v"(hi));
    return r;
}

// ---------------- h = x @ W^T (bf16 MFMA) -----------------------------------
// x-tile and W-slice staged coalesced into LDS as bf16 (cvt via v_cvt_pk),
// fragments read from LDS. Epilogue: s,t dots (log2-scaled), B-fragment-
// packed Bf store, pden zeroing. grid (NN/64, HH).
__global__ __launch_bounds__(256) void gemm_h(const float* __restrict__ x,
                                              const float* __restrict__ W,
                                              const float* __restrict__ a_src,
                                              const float* __restrict__ a_dst,
                                              float* __restrict__ s,
                                              float* __restrict__ T_T,
                                              uint16_t* __restrict__ Bf,
                                              float* __restrict__ pden) {
    __shared__ uint16_t xs[64][264];              // 33 KB
    __shared__ uint16_t wsl[64][264];             // 33 KB
    const int tid = threadIdx.x;
    if (blockIdx.y == 0) pden[blockIdx.x * 256 + tid] = 0.f;  // 64 blk * 256 = NN*HH
    const int i0g = blockIdx.x * 64;
    const int f0 = blockIdx.y * 64;
    const int hh = blockIdx.y;                    // head index
    const float* xsrc = x + (size_t)i0g * FF;     // contiguous 64x256 tile
    const float* wsrc = W + (size_t)f0 * FF;      // contiguous 64x256 slice
    {
        const int rw = tid >> 6, c4 = (tid & 63) * 4;
#pragma unroll
        for (int p = 0; p < 16; p++) {
            float4 vx = ((const float4*)xsrc)[p * 256 + tid];
            float4 vw = ((const float4*)wsrc)[p * 256 + tid];
            *(uint2*)&xs[p * 4 + rw][c4] =
                make_uint2(cvtpk(vx.x, vx.y), cvtpk(vx.z, vx.w));
            *(uint2*)&wsl[p * 4 + rw][c4] =
                make_uint2(cvtpk(vw.x, vw.y), cvtpk(vw.z, vw.w));
        }
    }
    __syncthreads();
    const int w = tid >> 6, l = tid & 63;
    const int m = l & 15, q = l >> 4;             // 16x16x32: m=l&15, k=q*8+j
    const int i0 = i0g + w * 16;
    f32x4 acc[4];
#pragma unroll
    for (int n = 0; n < 4; n++)
#pragma unroll
        for (int r = 0; r < 4; r++) acc[n][r] = 0.f;
    const uint16_t* ax = &xs[w * 16 + m][q * 8];
#pragma unroll
    for (int k0 = 0; k0 < 8; k0++) {
        short8 af = *(const short8*)(ax + k0 * 32);
#pragma unroll
        for (int n = 0; n < 4; n++) {
            short8 bf = *(const short8*)&wsl[n * 16 + m][k0 * 32 + q * 8];
            acc[n] = __builtin_amdgcn_mfma_f32_16x16x32_bf16(af, bf, acc[n], 0, 0, 0);
        }
    }
    // ---- fused epilogue: s,t dots (log2-scaled) ----
    const float* as = a_src + hh * DD;
    const float* ad = a_dst + hh * DD;
    float av[4], dv[4];
#pragma unroll
    for (int n = 0; n < 4; n++) { av[n] = as[n * 16 + m]; dv[n] = ad[n * 16 + m]; }
#pragma unroll
    for (int r = 0; r < 4; r++) {
        float vs = 0.f, vd = 0.f;
#pragma unroll
        for (int n = 0; n < 4; n++) {
            vs = fmaf(acc[n][r], av[n], vs);
            vd = fmaf(acc[n][r], dv[n], vd);
        }
#pragma unroll
        for (int off = 1; off < 16; off <<= 1) {  // reduce across m
            vs += __shfl_xor(vs, off, 64);
            vd += __shfl_xor(vd, off, 64);
        }
        if (m == 0) {
            const int i = i0 + q * 4 + r;         // C: col=l&15 -> f, row=q*4+r -> i
            s[(size_t)i * HH + hh] = vs * LOG2E;  // log2-domain scores
            T_T[(size_t)hh * NN + i] = vd * LOG2E;
        }
    }
    // ---- fused epilogue: B-fragment-packed store ----
    // value acc[n][r] = h[i=i0+q*4+r][f=f0+n*16+m]; iblk=i/8, jj=i%8.
    const int iblk = blockIdx.x * 8 + w * 2 + (q >> 1);
    const int jjo  = (q & 1) * 4;                 // r=0..3 contiguous
#pragma unroll
    for (int n = 0; n < 4; n++) {
        *(uint2*)(Bf + (((size_t)hh * NB + iblk) * 64 + n * 16 + m) * 8 + jjo) =
            make_uint2(cvtpk(acc[n][0], acc[n][1]), cvtpk(acc[n][2], acc[n][3]));
    }
}

// ---------------- fused scores -> exp2 -> P -> MFMA PV ----------------------
// block: 32 i x 512 j-slice; wave w = head w. adj double-buffered in LDS
// (CJ=128, one barrier per chunk) with register prefetch one chunk ahead.
// LDS layout: adj value (j,i) stored at [j][i ^ ((j>>4)<<2)] (bank-XOR,
// stride 32, no pad): R6 counters showed 1.57M write conflicts (j=16r+c
// collapses to 2 residues mod 32 -> 4-way); swizzle makes writes 2-way
// (free) and keeps reads (m ^ const = permutation) conflict-free. LDS drops
// to exactly 32 KB -> 5 blocks/CU capacity. P-pack via v_cvt_pk_bf16_f32
// (1 instr vs 4). Scores in log2-domain, exp2 direct.
__global__ __launch_bounds__(256, 4) void gat_main(
    const float* __restrict__ adj, const uint16_t* __restrict__ Bf,
    const float* __restrict__ s, const float* __restrict__ T_T,
    float* __restrict__ pden, uint16_t* __restrict__ part) {
    __shared__ float adj_s[2][CJ][32];            // 2 x 128 x 32 x 4B = 32 KB
    const int tid = threadIdx.x;
    const int w = tid >> 6, l = tid & 63;
    const int m = l & 31, q = l >> 5;             // 32x32x16: m=l&31, k=q*8+j
    // bijective XCD swizzle (nwg % 8 == 0): same-XCD blocks share a j-slice
    constexpr int NWG = (NN / ITILE) * NS;
    const int orig = blockIdx.y * (NN / ITILE) + blockIdx.x;
    const int swz = (orig & 7) * (NWG / 8) + (orig >> 3);
    const int i0 = (swz & (NN / ITILE - 1)) * ITILE;
    const int sl = swz / (NN / ITILE);
    const int jb = sl * JR;

    const float sS = s[(size_t)(i0 + m) * HH + w];  // *log2e already
    const float sB = NEG * sS;
    float den = 0.f;
    f32x16 acc0, acc1;
#pragma unroll
    for (int r = 0; r < 16; r++) { acc0[r] = 0.f; acc1[r] = 0.f; }
    const float* trow = T_T + (size_t)w * NN;
    const uint16_t* bbase = Bf + (size_t)w * NB * 512;  // 512 u16 per jblk

    // staging geometry: thread stages adj[i0+is][jc+j16 .. +15] (4 float4)
    const int is = tid >> 3, r7 = tid & 7, j16 = r7 * 16;
    const int colw = is ^ (r7 << 2);              // swizzled LDS column
    const float* arow = adj + (size_t)(i0 + is) * NN + j16;

    float4 pre[4];
#pragma unroll
    for (int c4 = 0; c4 < 4; c4++) pre[c4] = *(const float4*)(arow + jb + c4 * 4);
#pragma unroll
    for (int c4 = 0; c4 < 4; c4++) {
        adj_s[0][j16 + c4 * 4 + 0][colw] = pre[c4].x;
        adj_s[0][j16 + c4 * 4 + 1][colw] = pre[c4].y;
        adj_s[0][j16 + c4 * 4 + 2][colw] = pre[c4].z;
        adj_s[0][j16 + c4 * 4 + 3][colw] = pre[c4].w;
    }
#pragma unroll
    for (int c4 = 0; c4 < 4; c4++) pre[c4] = *(const float4*)(arow + jb + CJ + c4 * 4);
    __syncthreads();

    for (int c = 0; c < NCH; ++c) {
        const int jc = jb + c * CJ;
        const int cur = c & 1;
        if (c + 1 < NCH) {                        // write chunk c+1 into other buf
            const int nb = cur ^ 1;
#pragma unroll
            for (int c4 = 0; c4 < 4; c4++) {
                adj_s[nb][j16 + c4 * 4 + 0][colw] = pre[c4].x;
                adj_s[nb][j16 + c4 * 4 + 1][colw] = pre[c4].y;
                adj_s[nb][j16 + c4 * 4 + 2][colw] = pre[c4].z;
                adj_s[nb][j16 + c4 * 4 + 3][colw] = pre[c4].w;
            }
            if (c + 2 < NCH) {                    // prefetch chunk c+2 -> regs
#pragma unroll
                for (int c4 = 0; c4 < 4; c4++)
                    pre[c4] = *(const float4*)(arow + jc + 2 * CJ + c4 * 4);
            }
        }
#pragma unroll
        for (int kk = 0; kk < CJ; kk += 16) {
            const int jg = jc + kk + q * 8;       // lane's first j (global)
            const int jblk = ((jc + kk) >> 3) + q;
            const int cmv = m ^ (((kk >> 4) & 7) << 2);   // read col (swizzled)
            float4 t0 = *(const float4*)(trow + jg);
            float4 t1 = *(const float4*)(trow + jg + 4);
            short8 bf0 = *(const short8*)(bbase + (size_t)jblk * 512 + m * 8);
            short8 bf1 = *(const short8*)(bbase + (size_t)jblk * 512 + (32 + m) * 8);
            float tt[8] = {t0.x, t0.y, t0.z, t0.w, t1.x, t1.y, t1.z, t1.w};
            union { uint32_t u[4]; short8 v; } afu;
#pragma unroll
            for (int jj = 0; jj < 8; jj += 2) {
                const int rr = kk + q * 8 + jj;
                float a0 = adj_s[cur][rr][cmv], a1 = adj_s[cur][rr + 1][cmv];
                float tv0 = tt[jj], tv1 = tt[jj + 1];
                // lrelu in log2 domain: max(S+T, 0.2*(S+T)); exp2 direct
                float x0 = sS + tv0,           x1 = sS + tv1;
                float z0 = fmaf(NEG, tv0, sB), z1 = fmaf(NEG, tv1, sB);
                float lr0 = fmaxf(x0, z0), lr1 = fmaxf(x1, z1);
                float e0, e1;
                asm("v_exp_f32 %0, %1" : "=v"(e0) : "v"(lr0));
                asm("v_exp_f32 %0, %1" : "=v"(e1) : "v"(lr1));
                e0 = (a0 > 0.f) ? e0 : 0.f;
                e1 = (a1 > 0.f) ? e1 : 0.f;
                den += e0 + e1;
                afu.u[jj >> 1] = cvtpk(e0 * a0, e1 * a1);
            }
            acc0 = __builtin_amdgcn_mfma_f32_32x32x16_bf16(afu.v, bf0, acc0, 0, 0, 0);
            acc1 = __builtin_amdgcn_mfma_f32_32x32x16_bf16(afu.v, bf1, acc1, 0, 0, 0);
        }
        __syncthreads();
    }
    den += __shfl_down(den, 32, 64);              // lanes l and l+32 share m
    if (l < 32) atomicAdd(&pden[(size_t)(i0 + m) * HH + w], den);
    uint16_t* pbase = part + (size_t)sl * NN * FF;
#pragma unroll
    for (int reg = 0; reg < 16; reg++) {
        int row = (reg & 3) + 8 * (reg >> 2) + 4 * q;  // C: col=l&31, verified m74
        pbase[(size_t)(i0 + row) * FF + w * DD + m]      = bf16_rh(acc0[reg]);
        pbase[(size_t)(i0 + row) * FF + w * DD + 32 + m] = bf16_rh(acc1[reg]);
    }
}

// ---------------- sum slice partials, divide by denom (vectorized) ----------
// block: 8 i-rows x 32 lanes; thread handles 8 consecutive f via short8 (16B).
__global__ __launch_bounds__(256) void finalize(const uint16_t* __restrict__ part,
                                                const float* __restrict__ pden,
                                                float* __restrict__ out) {
    const int i = blockIdx.x * 8 + (threadIdx.x >> 5);
    const int f8 = (threadIdx.x & 31) * 8;
    float acc[8];
#pragma unroll
    for (int e = 0; e < 8; e++) acc[e] = 0.f;
#pragma unroll
    for (int sl = 0; sl < NS; sl++) {
        union { short8 v; uint16_t u[8]; } b;
        b.v = *(const short8*)(part + (size_t)sl * NN * FF + (size_t)i * FF + f8);
#pragma unroll
        for (int e = 0; e < 8; e++)
            acc[e] += __uint_as_float(((uint32_t)b.u[e]) << 16);
    }
    float d = pden[(size_t)i * HH + (f8 >> 6)];
    float inv = (d > 0.f) ? 1.f / d : 0.f;
    *(float4*)(out + (size_t)i * FF + f8) =
        make_float4(acc[0] * inv, acc[1] * inv, acc[2] * inv, acc[3] * inv);
    *(float4*)(out + (size_t)i * FF + f8 + 4) =
        make_float4(acc[4] * inv, acc[5] * inv, acc[6] * inv, acc[7] * inv);
}

extern "C" void kernel_launch(void* const* d_in, const int* in_sizes, int n_in,
                              void* d_out, int out_size, void* d_ws, size_t ws_size,
                              hipStream_t stream) {
    const float* x     = (const float*)d_in[0];
    const float* adj   = (const float*)d_in[1];
    const float* W     = (const float*)d_in[2];
    const float* a_src = (const float*)d_in[3];
    const float* a_dst = (const float*)d_in[4];
    float* out = (float*)d_out;

    char* ws = (char*)d_ws;
    uint16_t* Bf   = (uint16_t*)ws;                                // 2 MB
    float*    s    = (float*)(ws + (2u << 20));                    // 64 KB
    float*    T_T  = s + (size_t)NN * HH;                          // 64 KB
    float*    pden = T_T + (size_t)HH * NN;                        // 64 KB
    uint16_t* part = (uint16_t*)(ws + (3u << 20));                 // NS * 2 MB = 16 MB

    gemm_h<<<dim3(NN / 64, HH), 256, 0, stream>>>(x, W, a_src, a_dst, s, T_T, Bf, pden);
    gat_main<<<dim3(NN / ITILE, NS), 256, 0, stream>>>(adj, Bf, s, T_T, pden, part);
    finalize<<<NN / 8, 256, 0, stream>>>(part, pden, out);
}